// Round 1
// baseline (102.183 us; speedup 1.0000x reference)
//
#include <hip/hip_runtime.h>

// Problem constants (reference: B=8, N=16384, F=128, P=28)
#define BDIM  8
#define NDIM  16384
#define FDIM  128
#define PDIM  28
#define KPAD  896              // 28 p-steps * 32 padded q
#define MPTS  (BDIM * NDIM)    // 131072 points

typedef _Float16 half8  __attribute__((ext_vector_type(8)));
typedef float    floatx4 __attribute__((ext_vector_type(4)));

// ---------------------------------------------------------------------------
// Prep: IF [F][P][P] fp32  ->  IFt [F][KPAD] f16, k = p*32 + q, zero pad q>=28
// ---------------------------------------------------------------------------
__global__ __launch_bounds__(256) void prep_ift(const float* __restrict__ IF,
                                                _Float16* __restrict__ IFt) {
    int idx = blockIdx.x * 256 + threadIdx.x;     // 0 .. 128*896-1
    int f = idx / KPAD;
    int k = idx - f * KPAD;
    int p = k >> 5;
    int q = k & 31;
    float v = (q < PDIM) ? IF[f * (PDIM * PDIM) + p * PDIM + q] : 0.0f;
    IFt[idx] = (_Float16)v;
}

// ---------------------------------------------------------------------------
// Main: C[m,f] = sum_k W[m,k] * IFt[k,f],  W[m, p*32+q] = k0[m,p]*k1[m,q]
// Block: 128 points x 128 features, 4 waves (2x2), wave tile 64x64,
// mfma_f32_16x16x32_f16, K-loop = 28 steps of 32 (one p per step).
// ---------------------------------------------------------------------------
__global__ __launch_bounds__(256, 4) void feats_kernel(
    const float* __restrict__ x,       // [MPTS][2]
    const float* __restrict__ sigma,   // [1] log lengthscale
    const _Float16* __restrict__ IFt,  // [FDIM][KPAD] f16
    float* __restrict__ out)           // [MPTS][FDIM]
{
    // k0: fp32, stride 29 floats  -> 16 lanes hit 16 distinct banks (29m mod 32)
    // k1/bs: f16, stride 40 (80B) -> rows stay 16B-aligned; 2-way bank alias = free
    __shared__ float                 k0s[128 * 29];
    __shared__ __align__(16) _Float16 k1s[128 * 40];
    __shared__ __align__(16) _Float16 bs [128 * 40];

    const int tid  = threadIdx.x;
    const int lane = tid & 63;
    const int wave = tid >> 6;
    const int wm   = wave & 1;          // wave row (points)
    const int wn   = wave >> 1;         // wave col (features)
    const int ln15 = lane & 15;
    const int quad = lane >> 4;

    const float ls    = __expf(sigma[0]);
    const float inv   = 0.5f / (ls * ls);
    const float gstep = 0.998f / 27.0f;

    // ---- prologue: build k0 (threads 0..127) and k1 (threads 128..255) ----
    {
        const int ptl = tid & 127;
        const int ptg = blockIdx.x * 128 + ptl;
        if (tid < 128) {
            const float x0 = x[2 * ptg + 0];
            #pragma unroll
            for (int p = 0; p < PDIM; p++) {
                float d = (0.001f + p * gstep) - x0;
                k0s[ptl * 29 + p] = __expf(-inv * d * d);
            }
        } else {
            const float x1 = x[2 * ptg + 1];
            #pragma unroll
            for (int q = 0; q < PDIM; q++) {
                float d = (0.001f + q * gstep) - x1;
                k1s[ptl * 40 + q] = (_Float16)__expf(-inv * d * d);
            }
            #pragma unroll
            for (int q = PDIM; q < 32; q++)
                k1s[ptl * 40 + q] = (_Float16)0.0f;   // zero pad (read by quad 3)
        }
    }
    __syncthreads();

    // ---- hoisted k1 A-fragments: lane addresses are K-step invariant ----
    // A layout (16x16x32): A[m = lane&15][k = quad*8 + j]; within a K-step
    // k local = q, so lane needs k1[m][quad*8 .. +7] -> one ds_read_b128.
    half8 k1f[4];
    int   k0base[4];
    #pragma unroll
    for (int mt = 0; mt < 4; mt++) {
        const int mrow = wm * 64 + mt * 16 + ln15;
        k1f[mt]    = *(const half8*)&k1s[mrow * 40 + quad * 8];
        k0base[mt] = mrow * 29;
    }

    floatx4 acc[4][4];
    #pragma unroll
    for (int mt = 0; mt < 4; mt++)
        #pragma unroll
        for (int nt = 0; nt < 4; nt++)
            acc[mt][nt] = (floatx4){0.0f, 0.0f, 0.0f, 0.0f};

    // ---- B staging: slice [128 f][32 k] f16 = 8KB per K-step, 2 chunks/thread,
    //      prefetched one step ahead into registers ----
    const uint4* gI = (const uint4*)IFt;            // 8 f16 per uint4
    const int c0 = tid, c1 = tid + 256;             // chunk ids 0..511
    const int f0 = c0 >> 2, cq0 = c0 & 3;
    const int f1 = c1 >> 2, cq1 = c1 & 3;
    uint4* bsw0 = (uint4*)&bs[f0 * 40 + cq0 * 8];
    uint4* bsw1 = (uint4*)&bs[f1 * 40 + cq1 * 8];
    // uint4 index of (f, kk, cq): f*112 + kk*4 + cq
    uint4 pre0 = gI[f0 * 112 + cq0];
    uint4 pre1 = gI[f1 * 112 + cq1];

    #pragma unroll 1
    for (int kk = 0; kk < PDIM; kk++) {             // kk == p
        __syncthreads();                            // bs free (prev reads done)
        *bsw0 = pre0;
        *bsw1 = pre1;
        if (kk < PDIM - 1) {
            pre0 = gI[f0 * 112 + (kk + 1) * 4 + cq0];
            pre1 = gI[f1 * 112 + (kk + 1) * 4 + cq1];
        }
        __syncthreads();                            // bs ready

        // B fragments: B[k = quad*8+j][n = lane&15] <- bs[n][quad*8+j]
        half8 bf[4];
        #pragma unroll
        for (int nt = 0; nt < 4; nt++) {
            const int nrow = wn * 64 + nt * 16 + ln15;
            bf[nt] = *(const half8*)&bs[nrow * 40 + quad * 8];
        }

        #pragma unroll
        for (int mt = 0; mt < 4; mt++) {
            const float    k0v = k0s[k0base[mt] + kk];   // broadcast-ish read
            const _Float16 kh  = (_Float16)k0v;
            const half8    af  = k1f[mt] * kh;           // 4x v_pk_mul_f16
            #pragma unroll
            for (int nt = 0; nt < 4; nt++) {
                acc[mt][nt] = __builtin_amdgcn_mfma_f32_16x16x32_f16(
                    af, bf[nt], acc[mt][nt], 0, 0, 0);
            }
        }
    }

    // ---- epilogue: C/D layout col = lane&15 (feature), row = quad*4 + r ----
    #pragma unroll
    for (int mt = 0; mt < 4; mt++) {
        const int row0 = blockIdx.x * 128 + wm * 64 + mt * 16 + quad * 4;
        #pragma unroll
        for (int nt = 0; nt < 4; nt++) {
            const int col = wn * 64 + nt * 16 + ln15;
            float* op = out + (size_t)row0 * FDIM + col;
            #pragma unroll
            for (int r = 0; r < 4; r++)
                __builtin_nontemporal_store(acc[mt][nt][r], op + (size_t)r * FDIM);
        }
    }
}

// ---------------------------------------------------------------------------
extern "C" void kernel_launch(void* const* d_in, const int* in_sizes, int n_in,
                              void* d_out, int out_size, void* d_ws, size_t ws_size,
                              hipStream_t stream) {
    const float* x     = (const float*)d_in[0];   // [8,16384,2]
    const float* sigma = (const float*)d_in[1];   // [1]
    const float* IF    = (const float*)d_in[2];   // [128,28,28]
    float* out = (float*)d_out;                   // [8,16384,128] fp32

    // d_ws: IFt f16 [128][896] = 229376 bytes
    _Float16* IFt = (_Float16*)d_ws;

    prep_ift<<<(FDIM * KPAD) / 256, 256, 0, stream>>>(IF, IFt);          // 448 blocks
    feats_kernel<<<MPTS / 128, 256, 0, stream>>>(x, sigma, IFt, out);    // 1024 blocks
}